// Round 7
// baseline (216.001 us; speedup 1.0000x reference)
//
#include <hip/hip_runtime.h>
#include <cmath>

constexpr int ISIZE = 512;
constexpr int REC   = 1024;
constexpr int NACT  = 18;
constexpr int BS    = 64;
constexpr float CLIPVAL = 2.0f;
constexpr int NSLOT = 17;   // 16 hebb i-chunk partials + 1 x@W0^T partial
constexpr int GB    = 8;    // batches per pipeline group (33.6 MB hebb slice)
constexpr int NG    = BS / GB;  // 8 groups

// block-range layout inside each pipelined dispatch
constexpr int NB_P2 = 128;              // ids [0,128)    : pass2 on group gP2
constexpr int NB_H  = GB;               // ids [128,136)  : head on group gH
constexpr int NB_P1 = 128;              // ids [136,264)  : pass1 on group gP1
constexpr int NB_XG = 64;               // ids [264,328)  : x@W0^T (dispatch 0)
constexpr int GRID  = NB_P2 + NB_H + NB_P1 + NB_XG;  // 328

typedef float f4 __attribute__((ext_vector_type(4)));

__device__ __forceinline__ void nt_store(f4* p, f4 v) {
#if __has_builtin(__builtin_nontemporal_store)
  __builtin_nontemporal_store(v, p);
#else
  *p = v;
#endif
}

// ===========================================================================
// One pipelined step: P2(gP2) | H(gH) | P1(gP1) | XG(if doXG).
// P2 blocks first in id order so their (L3-resident) reads start before
// P1 floods the cache with the next slice.
// ===========================================================================
__global__ __launch_bounds__(256) void k_step(
    const float* __restrict__ x,    const float* __restrict__ rv,
    const float* __restrict__ hebb, const float* __restrict__ w,
    const float* __restrict__ alpha,const float* __restrict__ W0,
    const float* __restrict__ b0,   const float* __restrict__ W1,
    const float* __restrict__ b1,   const float* __restrict__ h2w,
    const float* __restrict__ h2b,  const float* __restrict__ mw,
    const float* __restrict__ mb,   float* __restrict__ part,
    float* __restrict__ g,          float* __restrict__ hact,
    float* __restrict__ act_dis,    float* __restrict__ out,
    int gP1, int gH, int gP2, int doXG) {
  const int id = blockIdx.x;
  const int t  = threadIdx.x;

  if (id < NB_P2) {
    // --------------------------------------------------------------- pass 2
    if (gP2 < 0) return;
    const int b  = gP2 * GB + (id & 7);
    const int i0 = (id >> 3) * 64;           // 16 chunks x 64 rows
    const int j0 = t * 4;
    const f4 gv = *(const f4*)(g + (size_t)b * REC + j0);
    const float* __restrict__ rvb = rv + (size_t)b * REC + i0;
    const size_t base = ((size_t)b * REC + i0) * REC + j0;
#pragma unroll 4
    for (int ii = 0; ii < 64; ++ii) {
      const float r = rvb[ii];
      const f4 hv = *(const f4*)(hebb + base + (size_t)ii * REC);
      f4 o;
      o.x = fminf(fmaxf(fmaf(r, gv.x, hv.x), -CLIPVAL), CLIPVAL);
      o.y = fminf(fmaxf(fmaf(r, gv.y, hv.y), -CLIPVAL), CLIPVAL);
      o.z = fminf(fmaxf(fmaf(r, gv.z, hv.z), -CLIPVAL), CLIPVAL);
      o.w = fminf(fmaxf(fmaf(r, gv.w, hv.w), -CLIPVAL), CLIPVAL);
      nt_store((f4*)(out + base + (size_t)ii * REC), o);
    }

  } else if (id < NB_P2 + NB_H) {
    // ----------------------------------------------------------------- head
    if (gH < 0) return;
    const int b  = gH * GB + (id - NB_P2);
    const int j0 = t * 4;
    __shared__ float hsh[REC];
    __shared__ float logits_s[32];
    __shared__ float myeta_s;

    f4 s = *(const f4*)(b0 + j0);
#pragma unroll
    for (int sl = 0; sl < NSLOT; ++sl) {
      const f4 p = *(const f4*)(part + ((size_t)b * NSLOT + sl) * REC + j0);
      s.x += p.x; s.y += p.y; s.z += p.z; s.w += p.w;
    }
    f4 h4;
    h4.x = tanhf(s.x); h4.y = tanhf(s.y); h4.z = tanhf(s.z); h4.w = tanhf(s.w);
    *(f4*)(hact + (size_t)b * REC + j0) = h4;
    *(f4*)(&hsh[j0]) = h4;
    __syncthreads();

    const int wid = t >> 6, ln = t & 63;
    for (int a = wid; a < NACT; a += 4) {
      const float* __restrict__ w1a = W1 + (size_t)a * REC;
      float p = 0.f;
#pragma unroll
      for (int c = 0; c < 16; ++c) p = fmaf(hsh[c * 64 + ln], w1a[c * 64 + ln], p);
#pragma unroll
      for (int off = 32; off; off >>= 1) p += __shfl_down(p, off);
      if (ln == 0) logits_s[a] = p + b1[a];
    }
    if (wid == 3) {
      float p = 0.f;
#pragma unroll
      for (int c = 0; c < 16; ++c) p = fmaf(hsh[c * 64 + ln], h2w[c * 64 + ln], p);
#pragma unroll
      for (int off = 32; off; off >>= 1) p += __shfl_down(p, off);
      if (ln == 0) myeta_s = tanhf(p + h2b[0]);
    }
    __syncthreads();

    if (t == 0) {
      float m = logits_s[0];
      for (int a = 1; a < NACT; ++a) m = fmaxf(m, logits_s[a]);
      float e[NACT];
      float ssum = 0.f;
      for (int a = 0; a < NACT; ++a) { e[a] = expf(logits_s[a] - m); ssum += e[a]; }
      const float inv = 1.f / ssum;
      for (int a = 0; a < NACT; ++a) act_dis[(size_t)b * NACT + a] = e[a] * inv;
    }
    __syncthreads();

    const float me = myeta_s;
    const f4 mwv = *(const f4*)(mw + j0);
    const f4 mbv = *(const f4*)(mb + j0);
    const f4 hh  = *(const f4*)(&hsh[j0]);
    f4 gv;
    gv.x = fmaf(me, mwv.x, mbv.x) * hh.x;
    gv.y = fmaf(me, mwv.y, mbv.y) * hh.y;
    gv.z = fmaf(me, mwv.z, mbv.z) * hh.z;
    gv.w = fmaf(me, mwv.w, mbv.w) * hh.w;
    *(f4*)(g + (size_t)b * REC + j0) = gv;

  } else if (id < NB_P2 + NB_H + NB_P1) {
    // --------------------------------------------------------------- pass 1
    if (gP1 < 0) return;
    const int idx = id - (NB_P2 + NB_H);     // 0..127
    const int bg  = idx & 1;                 // 2 half-groups of 4 batches
    const int jq  = (idx >> 1) & 3;          // 256-j quarter
    const int ic  = idx >> 3;                // 0..15, 64 i-rows
    const int b0i = gP1 * GB + bg * 4;
    const int i0  = ic * 64;
    const int jl  = t & 63, blane = t >> 6;
    const int j0  = jq * 256 + jl * 4;
    const int ba  = b0i + blane;             // one batch per wave

    __shared__ float rvs[4][64];
    rvs[t >> 6][t & 63] = rv[(size_t)(b0i + (t >> 6)) * REC + i0 + (t & 63)];
    __syncthreads();

    f4 acc = {0.f, 0.f, 0.f, 0.f};
    const float* __restrict__ wp = w     + (size_t)i0 * REC + j0;
    const float* __restrict__ ap = alpha + (size_t)i0 * REC + j0;
    const float* __restrict__ hp = hebb + ((size_t)ba * REC + i0) * REC + j0;
    const float* __restrict__ rs = &rvs[blane][0];
#pragma unroll 4
    for (int ii = 0; ii < 64; ++ii) {
      const f4 wv = *(const f4*)(wp + (size_t)ii * REC);
      const f4 av = *(const f4*)(ap + (size_t)ii * REC);
      const f4 hv = *(const f4*)(hp + (size_t)ii * REC);
      const float r = rs[ii];
      acc.x = fmaf(r, fmaf(av.x, hv.x, wv.x), acc.x);
      acc.y = fmaf(r, fmaf(av.y, hv.y, wv.y), acc.y);
      acc.z = fmaf(r, fmaf(av.z, hv.z, wv.z), acc.z);
      acc.w = fmaf(r, fmaf(av.w, hv.w, wv.w), acc.w);
    }
    *(f4*)(part + ((size_t)ba * NSLOT + ic) * REC + j0) = acc;

  } else {
    // -------------------------------------------- x @ W0^T (dispatch 0 only)
    if (!doXG) return;
    const int idx = id - (NB_P2 + NB_H + NB_P1);  // 0..63
    const int jt = idx & 31, bh = idx >> 5;
    const int J0 = jt * 32, B0 = bh * 32;
    const int tx = t & 31, ty = t >> 5;
    __shared__ float w0s[32][33];
    __shared__ float xs[32][33];
    float acc[4] = {0.f, 0.f, 0.f, 0.f};
    for (int kk = 0; kk < ISIZE; kk += 32) {
#pragma unroll
      for (int r = 0; r < 32; r += 8) {
        w0s[tx][ty + r] = W0[(size_t)(J0 + ty + r) * ISIZE + kk + tx];
        xs[ty + r][tx]  = x [(size_t)(B0 + ty + r) * ISIZE + kk + tx];
      }
      __syncthreads();
#pragma unroll
      for (int k = 0; k < 32; ++k) {
        const float w0v = w0s[k][tx];
#pragma unroll
        for (int q = 0; q < 4; ++q)
          acc[q] = fmaf(xs[ty * 4 + q][k], w0v, acc[q]);
      }
      __syncthreads();
    }
#pragma unroll
    for (int q = 0; q < 4; ++q)
      part[((size_t)(B0 + ty * 4 + q) * NSLOT + 16) * REC + J0 + tx] = acc[q];
  }
}

// ---------------------------------------------------------------------------
extern "C" void kernel_launch(void* const* d_in, const int* in_sizes, int n_in,
                              void* d_out, int out_size, void* d_ws, size_t ws_size,
                              hipStream_t stream) {
  const float* x     = (const float*)d_in[0];
  const float* rv    = (const float*)d_in[1];
  const float* hebb  = (const float*)d_in[2];
  const float* w     = (const float*)d_in[3];
  const float* alpha = (const float*)d_in[4];
  const float* W0    = (const float*)d_in[5];
  const float* b0    = (const float*)d_in[6];
  const float* W1    = (const float*)d_in[7];
  const float* b1    = (const float*)d_in[8];
  const float* h2w   = (const float*)d_in[9];
  const float* h2b   = (const float*)d_in[10];
  const float* mw    = (const float*)d_in[11];
  const float* mb    = (const float*)d_in[12];

  float* out_act  = (float*)d_out;               // 64*18
  float* out_hact = out_act + (size_t)BS * NACT; // 64*1024
  float* out_hebb = out_hact + (size_t)BS * REC; // 64*1024*1024

  float* part = (float*)d_ws;                    // 64*17*1024
  float* g    = part + (size_t)BS * NSLOT * REC; // 64*1024

  // Pipeline: dispatch k runs P2(k-2) | H(k-1) | P1(k)  (+XG at k=0).
  for (int k = 0; k < NG + 2; ++k) {
    const int gP1 = (k < NG) ? k : -1;
    const int gH  = (k >= 1 && k <= NG) ? k - 1 : -1;
    const int gP2 = (k >= 2) ? k - 2 : -1;
    const int doXG = (k == 0) ? 1 : 0;
    k_step<<<GRID, 256, 0, stream>>>(x, rv, hebb, w, alpha, W0, b0, W1, b1,
                                     h2w, h2b, mw, mb, part, g,
                                     out_hact, out_act, out_hebb,
                                     gP1, gH, gP2, doXG);
  }
}

// Round 8
// 213.161 us; speedup vs baseline: 1.0133x; 1.0133x over previous
//
#include <hip/hip_runtime.h>
#include <cmath>

constexpr int ISIZE = 512;
constexpr int REC   = 1024;
constexpr int NACT  = 18;
constexpr int BS    = 64;
constexpr float CLIPVAL = 2.0f;
constexpr int NSLOT = 17;   // 16 hebb i-chunk partials + 1 x@W0^T partial

typedef float f4 __attribute__((ext_vector_type(4)));

__device__ __forceinline__ void nt_store(f4* p, f4 v) {
#if __has_builtin(__builtin_nontemporal_store)
  __builtin_nontemporal_store(v, p);
#else
  *p = v;
#endif
}

// ===========================================================================
// K1: pass 1 (R3-proven, 576 blocks).
//   id 0..511 : hebb partials. (ic, jh, bg): 64 i-rows x 512 j x 4 batches;
//               thread: 4 j x 2 batches; bg fastest (w/alpha slice sharing).
//               Temporal order is ic-major => line age at end ~ f(i) only.
//   id 512..575: x @ W0^T (32x32 LDS-tiled) -> part slot 16.
// ===========================================================================
__global__ __launch_bounds__(256) void k_pass1(
    const float* __restrict__ rv, const float* __restrict__ hebb,
    const float* __restrict__ w, const float* __restrict__ alpha,
    const float* __restrict__ x, const float* __restrict__ W0,
    float* __restrict__ part) {
  const int id = blockIdx.x;
  const int t  = threadIdx.x;

  if (id < 512) {
    const int bg = id & 15;
    const int jh = (id >> 4) & 1;
    const int ic = id >> 5;
    const int b0i = bg * 4, i0 = ic * 64;
    const int jl = t & 127, bl = t >> 7;
    const int j0 = jh * 512 + jl * 4;
    const int ba = b0i + bl * 2;

    __shared__ float rvs[4][64];
    rvs[t >> 6][t & 63] = rv[(size_t)(b0i + (t >> 6)) * REC + i0 + (t & 63)];
    __syncthreads();

    f4 a0 = {0.f, 0.f, 0.f, 0.f}, a1 = {0.f, 0.f, 0.f, 0.f};
    const float* __restrict__ wp  = w     + (size_t)i0 * REC + j0;
    const float* __restrict__ ap  = alpha + (size_t)i0 * REC + j0;
    const float* __restrict__ hp0 = hebb + ((size_t)ba * REC + i0) * REC + j0;
    const float* __restrict__ hp1 = hp0 + (size_t)REC * REC;
    const float* __restrict__ r0s = &rvs[bl * 2][0];
    const float* __restrict__ r1s = &rvs[bl * 2 + 1][0];

#pragma unroll 4
    for (int ii = 0; ii < 64; ++ii) {
      const f4 wv = *(const f4*)(wp  + (size_t)ii * REC);
      const f4 av = *(const f4*)(ap  + (size_t)ii * REC);
      const f4 h0 = *(const f4*)(hp0 + (size_t)ii * REC);
      const f4 h1 = *(const f4*)(hp1 + (size_t)ii * REC);
      const float r0 = r0s[ii], r1 = r1s[ii];
      a0.x = fmaf(r0, fmaf(av.x, h0.x, wv.x), a0.x);
      a0.y = fmaf(r0, fmaf(av.y, h0.y, wv.y), a0.y);
      a0.z = fmaf(r0, fmaf(av.z, h0.z, wv.z), a0.z);
      a0.w = fmaf(r0, fmaf(av.w, h0.w, wv.w), a0.w);
      a1.x = fmaf(r1, fmaf(av.x, h1.x, wv.x), a1.x);
      a1.y = fmaf(r1, fmaf(av.y, h1.y, wv.y), a1.y);
      a1.z = fmaf(r1, fmaf(av.z, h1.z, wv.z), a1.z);
      a1.w = fmaf(r1, fmaf(av.w, h1.w, wv.w), a1.w);
    }
    *(f4*)(part + ((size_t)ba * NSLOT + ic) * REC + j0)       = a0;
    *(f4*)(part + ((size_t)(ba + 1) * NSLOT + ic) * REC + j0) = a1;

  } else {
    const int idx = id - 512;
    const int jt = idx & 31, bg2 = idx >> 5;
    const int J0 = jt * 32, B0 = bg2 * 32;
    const int tx = t & 31, ty = t >> 5;
    __shared__ float w0s[32][33];
    __shared__ float xs[32][33];
    float acc[4] = {0.f, 0.f, 0.f, 0.f};
    for (int kk = 0; kk < ISIZE; kk += 32) {
#pragma unroll
      for (int r = 0; r < 32; r += 8) {
        w0s[tx][ty + r] = W0[(size_t)(J0 + ty + r) * ISIZE + kk + tx];
        xs[ty + r][tx]  = x [(size_t)(B0 + ty + r) * ISIZE + kk + tx];
      }
      __syncthreads();
#pragma unroll
      for (int k = 0; k < 32; ++k) {
        const float w0v = w0s[k][tx];
#pragma unroll
        for (int q = 0; q < 4; ++q)
          acc[q] = fmaf(xs[ty * 4 + q][k], w0v, acc[q]);
      }
      __syncthreads();
    }
#pragma unroll
    for (int q = 0; q < 4; ++q)
      part[((size_t)(B0 + ty * 4 + q) * NSLOT + 16) * REC + J0 + tx] = acc[q];
  }
}

// ===========================================================================
// K2: persistent work-queue tail — head jobs (64, first) then hebb-update
// jobs (1024) ordered ic-DESCENDING (freshest L3 lines first).
// sync[0] = ticket; sync[1+b] = gflag[b].  Deadlock-free: H jobs precede all
// P2 jobs in the queue and have no in-kernel dependencies.
// ===========================================================================
constexpr int NJOBS2 = 64 + 1024;

__global__ __launch_bounds__(256, 2) void k_tail(
    const float* __restrict__ rv,  const float* __restrict__ hebb,
    const float* __restrict__ b0,  const float* __restrict__ W1,
    const float* __restrict__ b1,  const float* __restrict__ h2w,
    const float* __restrict__ h2b, const float* __restrict__ mw,
    const float* __restrict__ mb,  const float* __restrict__ part,
    float* __restrict__ g,         int* __restrict__ sync,
    float* __restrict__ hact,      float* __restrict__ act_dis,
    float* __restrict__ out) {
  const int t = threadIdx.x;
  __shared__ int s_job;
  __shared__ float hsh[REC];
  __shared__ float logits_s[32];
  __shared__ float myeta_s;

  for (;;) {
    __syncthreads();
    if (t == 0) s_job = atomicAdd(&sync[0], 1);
    __syncthreads();
    const int j = s_job;
    if (j >= NJOBS2) return;

    if (j < 64) {
      // ------------------------------------------------------------ head(b)
      const int b  = 63 - j;
      const int j0 = t * 4;

      f4 s = *(const f4*)(b0 + j0);
#pragma unroll
      for (int sl = 0; sl < NSLOT; ++sl) {
        const f4 p = *(const f4*)(part + ((size_t)b * NSLOT + sl) * REC + j0);
        s.x += p.x; s.y += p.y; s.z += p.z; s.w += p.w;
      }
      f4 h4;
      h4.x = tanhf(s.x); h4.y = tanhf(s.y); h4.z = tanhf(s.z); h4.w = tanhf(s.w);
      *(f4*)(hact + (size_t)b * REC + j0) = h4;
      *(f4*)(&hsh[j0]) = h4;
      __syncthreads();

      const int wid = t >> 6, ln = t & 63;
      for (int a = wid; a < NACT; a += 4) {
        const float* __restrict__ w1a = W1 + (size_t)a * REC;
        float p = 0.f;
#pragma unroll
        for (int c = 0; c < 16; ++c) p = fmaf(hsh[c * 64 + ln], w1a[c * 64 + ln], p);
#pragma unroll
        for (int off = 32; off; off >>= 1) p += __shfl_down(p, off);
        if (ln == 0) logits_s[a] = p + b1[a];
      }
      if (wid == 3) {
        float p = 0.f;
#pragma unroll
        for (int c = 0; c < 16; ++c) p = fmaf(hsh[c * 64 + ln], h2w[c * 64 + ln], p);
#pragma unroll
        for (int off = 32; off; off >>= 1) p += __shfl_down(p, off);
        if (ln == 0) myeta_s = tanhf(p + h2b[0]);
      }
      __syncthreads();

      if (t == 0) {
        float m = logits_s[0];
        for (int a = 1; a < NACT; ++a) m = fmaxf(m, logits_s[a]);
        float e[NACT];
        float ssum = 0.f;
        for (int a = 0; a < NACT; ++a) { e[a] = expf(logits_s[a] - m); ssum += e[a]; }
        const float inv = 1.f / ssum;
        for (int a = 0; a < NACT; ++a) act_dis[(size_t)b * NACT + a] = e[a] * inv;
      }
      __syncthreads();

      const float me = myeta_s;
      const f4 mwv = *(const f4*)(mw + j0);
      const f4 mbv = *(const f4*)(mb + j0);
      const f4 hh  = *(const f4*)(&hsh[j0]);
      f4 gv;
      gv.x = fmaf(me, mwv.x, mbv.x) * hh.x;
      gv.y = fmaf(me, mwv.y, mbv.y) * hh.y;
      gv.z = fmaf(me, mwv.z, mbv.z) * hh.z;
      gv.w = fmaf(me, mwv.w, mbv.w) * hh.w;
      float* __restrict__ gb = g + (size_t)b * REC + j0;
      __hip_atomic_store(&gb[0], gv.x, __ATOMIC_RELAXED, __HIP_MEMORY_SCOPE_AGENT);
      __hip_atomic_store(&gb[1], gv.y, __ATOMIC_RELAXED, __HIP_MEMORY_SCOPE_AGENT);
      __hip_atomic_store(&gb[2], gv.z, __ATOMIC_RELAXED, __HIP_MEMORY_SCOPE_AGENT);
      __hip_atomic_store(&gb[3], gv.w, __ATOMIC_RELAXED, __HIP_MEMORY_SCOPE_AGENT);
      __syncthreads();
      if (t == 0)
        __hip_atomic_store(&sync[1 + b], 1, __ATOMIC_RELEASE, __HIP_MEMORY_SCOPE_AGENT);

    } else {
      // --------------------------------------------------------- hebb(b,ic)
      const int r  = j - 64;
      const int ic = 15 - (r >> 6);       // descending: freshest lines first
      const int b  = 63 - (r & 63);
      const int i0 = ic * 64;
      const int j0 = t * 4;

      if (t == 0) {
        while (__hip_atomic_load(&sync[1 + b], __ATOMIC_ACQUIRE,
                                 __HIP_MEMORY_SCOPE_AGENT) == 0)
          __builtin_amdgcn_s_sleep(8);
      }
      __syncthreads();

      const float* __restrict__ gb = g + (size_t)b * REC + j0;
      f4 gv;
      gv.x = __hip_atomic_load(&gb[0], __ATOMIC_RELAXED, __HIP_MEMORY_SCOPE_AGENT);
      gv.y = __hip_atomic_load(&gb[1], __ATOMIC_RELAXED, __HIP_MEMORY_SCOPE_AGENT);
      gv.z = __hip_atomic_load(&gb[2], __ATOMIC_RELAXED, __HIP_MEMORY_SCOPE_AGENT);
      gv.w = __hip_atomic_load(&gb[3], __ATOMIC_RELAXED, __HIP_MEMORY_SCOPE_AGENT);

      const float* __restrict__ rvb = rv + (size_t)b * REC + i0;
      const size_t base = ((size_t)b * REC + i0) * REC + j0;
#pragma unroll 4
      for (int ii = 0; ii < 64; ++ii) {
        const float rr = rvb[ii];
        const f4 hv = *(const f4*)(hebb + base + (size_t)ii * REC);
        f4 o;
        o.x = fminf(fmaxf(fmaf(rr, gv.x, hv.x), -CLIPVAL), CLIPVAL);
        o.y = fminf(fmaxf(fmaf(rr, gv.y, hv.y), -CLIPVAL), CLIPVAL);
        o.z = fminf(fmaxf(fmaf(rr, gv.z, hv.z), -CLIPVAL), CLIPVAL);
        o.w = fminf(fmaxf(fmaf(rr, gv.w, hv.w), -CLIPVAL), CLIPVAL);
        nt_store((f4*)(out + base + (size_t)ii * REC), o);
      }
    }
  }
}

// ---------------------------------------------------------------------------
extern "C" void kernel_launch(void* const* d_in, const int* in_sizes, int n_in,
                              void* d_out, int out_size, void* d_ws, size_t ws_size,
                              hipStream_t stream) {
  const float* x     = (const float*)d_in[0];
  const float* rv    = (const float*)d_in[1];
  const float* hebb  = (const float*)d_in[2];
  const float* w     = (const float*)d_in[3];
  const float* alpha = (const float*)d_in[4];
  const float* W0    = (const float*)d_in[5];
  const float* b0    = (const float*)d_in[6];
  const float* W1    = (const float*)d_in[7];
  const float* b1    = (const float*)d_in[8];
  const float* h2w   = (const float*)d_in[9];
  const float* h2b   = (const float*)d_in[10];
  const float* mw    = (const float*)d_in[11];
  const float* mb    = (const float*)d_in[12];

  float* out_act  = (float*)d_out;               // 64*18
  float* out_hact = out_act + (size_t)BS * NACT; // 64*1024
  float* out_hebb = out_hact + (size_t)BS * REC; // 64*1024*1024

  float* part = (float*)d_ws;                    // 64*17*1024 floats
  float* g    = part + (size_t)BS * NSLOT * REC; // 64*1024 floats
  int*   sync = (int*)(g + (size_t)BS * REC);    // [0]=ticket, [1..64]=gflag

  hipMemsetAsync(sync, 0, (1 + BS) * sizeof(int), stream);
  k_pass1<<<576, 256, 0, stream>>>(rv, hebb, w, alpha, x, W0, part);
  k_tail<<<512, 256, 0, stream>>>(rv, hebb, b0, W1, b1, h2w, h2b, mw, mb,
                                  part, g, sync, out_hact, out_act, out_hebb);
}

// Round 9
// 159.441 us; speedup vs baseline: 1.3547x; 1.3369x over previous
//
#include <hip/hip_runtime.h>
#include <cmath>

constexpr int ISIZE = 512;
constexpr int REC   = 1024;
constexpr int NACT  = 18;
constexpr int BS    = 64;
constexpr float CLIPVAL = 2.0f;
constexpr int NSLOT = 17;   // 16 hebb i-chunk partials + 1 x@W0^T partial

typedef float f4 __attribute__((ext_vector_type(4)));

__device__ __forceinline__ f4 nt_load(const f4* p) {
#if __has_builtin(__builtin_nontemporal_load)
  return __builtin_nontemporal_load(p);
#else
  return *p;
#endif
}
__device__ __forceinline__ void nt_store(f4* p, f4 v) {
#if __has_builtin(__builtin_nontemporal_store)
  __builtin_nontemporal_store(v, p);
#else
  *p = v;
#endif
}

// ---------------------------------------------------------------------------
// Pass 1: 512 blocks = exactly 2 rounds on 256 CUs.
// Every block: hebb partials for (ic, jh, bg) — 64 i-rows x 512 j x 4 batches,
// thread: 4 j x 2 batches; bg fastest so 16 concurrent blocks share each
// w/alpha slice (4x cache-traffic cut, R3-proven).
// Blocks 0..63 additionally compute one 32x32 tile of x @ W0^T (slot 16)
// AFTER their streaming work — rides scheduling slack, no third round.
__global__ __launch_bounds__(256) void k_pass1(
    const float* __restrict__ rv, const float* __restrict__ hebb,
    const float* __restrict__ w, const float* __restrict__ alpha,
    const float* __restrict__ x, const float* __restrict__ W0,
    float* __restrict__ part) {
  const int id = blockIdx.x;
  const int t  = threadIdx.x;

  __shared__ float rvs[4][64];
  __shared__ float w0s[32][33];
  __shared__ float xs[32][33];

  {
    const int bg = id & 15;
    const int jh = (id >> 4) & 1;
    const int ic = id >> 5;              // 0..15
    const int b0i = bg * 4, i0 = ic * 64;
    const int jl = t & 127, bl = t >> 7;
    const int j0 = jh * 512 + jl * 4;
    const int ba = b0i + bl * 2;

    rvs[t >> 6][t & 63] = rv[(size_t)(b0i + (t >> 6)) * REC + i0 + (t & 63)];
    __syncthreads();

    f4 a0 = {0.f, 0.f, 0.f, 0.f}, a1 = {0.f, 0.f, 0.f, 0.f};
    const float* __restrict__ wp  = w     + (size_t)i0 * REC + j0;
    const float* __restrict__ ap  = alpha + (size_t)i0 * REC + j0;
    const float* __restrict__ hp0 = hebb + ((size_t)ba * REC + i0) * REC + j0;
    const float* __restrict__ hp1 = hp0 + (size_t)REC * REC;
    const float* __restrict__ r0s = &rvs[bl * 2][0];
    const float* __restrict__ r1s = &rvs[bl * 2 + 1][0];

#pragma unroll 4
    for (int ii = 0; ii < 64; ++ii) {
      const f4 wv = *(const f4*)(wp  + (size_t)ii * REC);
      const f4 av = *(const f4*)(ap  + (size_t)ii * REC);
      const f4 h0 = *(const f4*)(hp0 + (size_t)ii * REC);
      const f4 h1 = *(const f4*)(hp1 + (size_t)ii * REC);
      const float r0 = r0s[ii], r1 = r1s[ii];
      a0.x = fmaf(r0, fmaf(av.x, h0.x, wv.x), a0.x);
      a0.y = fmaf(r0, fmaf(av.y, h0.y, wv.y), a0.y);
      a0.z = fmaf(r0, fmaf(av.z, h0.z, wv.z), a0.z);
      a0.w = fmaf(r0, fmaf(av.w, h0.w, wv.w), a0.w);
      a1.x = fmaf(r1, fmaf(av.x, h1.x, wv.x), a1.x);
      a1.y = fmaf(r1, fmaf(av.y, h1.y, wv.y), a1.y);
      a1.z = fmaf(r1, fmaf(av.z, h1.z, wv.z), a1.z);
      a1.w = fmaf(r1, fmaf(av.w, h1.w, wv.w), a1.w);
    }
    *(f4*)(part + ((size_t)ba * NSLOT + ic) * REC + j0)       = a0;
    *(f4*)(part + ((size_t)(ba + 1) * NSLOT + ic) * REC + j0) = a1;
  }

  if (id < 64) {
    // x @ W0^T -> part slot 16. id: 32 j-tiles x 2 batch-halves.
    __syncthreads();
    const int jt = id & 31, bg2 = id >> 5;
    const int J0 = jt * 32, B0 = bg2 * 32;
    const int tx = t & 31, ty = t >> 5;
    float acc[4] = {0.f, 0.f, 0.f, 0.f};
    for (int kk = 0; kk < ISIZE; kk += 32) {
#pragma unroll
      for (int r = 0; r < 32; r += 8) {
        w0s[tx][ty + r] = W0[(size_t)(J0 + ty + r) * ISIZE + kk + tx];
        xs[ty + r][tx]  = x [(size_t)(B0 + ty + r) * ISIZE + kk + tx];
      }
      __syncthreads();
#pragma unroll
      for (int k = 0; k < 32; ++k) {
        const float w0v = w0s[k][tx];
#pragma unroll
        for (int q = 0; q < 4; ++q)
          acc[q] = fmaf(xs[ty * 4 + q][k], w0v, acc[q]);
      }
      __syncthreads();
    }
#pragma unroll
    for (int q = 0; q < 4; ++q)
      part[((size_t)(B0 + ty * 4 + q) * NSLOT + 16) * REC + J0 + tx] = acc[q];
  }
}

// ---------------------------------------------------------------------------
// Per-batch head, 1024 threads (t == j): reduce 17 partials + b0 -> tanh ->
// hactiv; logits (wave-per-action), myeta, softmax, g.  (R3-proven)
__global__ __launch_bounds__(1024) void k_head(
    const float* __restrict__ part, const float* __restrict__ b0,
    const float* __restrict__ W1, const float* __restrict__ b1,
    const float* __restrict__ h2w, const float* __restrict__ h2b,
    const float* __restrict__ mw, const float* __restrict__ mb,
    float* __restrict__ hact, float* __restrict__ act_dis,
    float* __restrict__ g) {
  const int b = blockIdx.x;
  const int t = threadIdx.x;
  __shared__ float hsh[REC];
  __shared__ float logits_s[32];
  __shared__ float myeta_s;

  float s = b0[t];
  const float* __restrict__ pb = part + (size_t)b * NSLOT * REC + t;
#pragma unroll
  for (int sl = 0; sl < NSLOT; ++sl) s += pb[(size_t)sl * REC];
  const float h = tanhf(s);
  hact[(size_t)b * REC + t] = h;
  hsh[t] = h;
  __syncthreads();

  const int wv = t >> 6, ln = t & 63;
  for (int a = wv; a < NACT; a += 16) {
    const float* __restrict__ w1a = W1 + (size_t)a * REC;
    float p = 0.f;
#pragma unroll
    for (int c = 0; c < 16; ++c) p = fmaf(hsh[c * 64 + ln], w1a[c * 64 + ln], p);
#pragma unroll
    for (int off = 32; off; off >>= 1) p += __shfl_down(p, off);
    if (ln == 0) logits_s[a] = p + b1[a];
  }
  if (wv == 0) {
    float p = 0.f;
#pragma unroll
    for (int c = 0; c < 16; ++c) p = fmaf(hsh[c * 64 + ln], h2w[c * 64 + ln], p);
#pragma unroll
    for (int off = 32; off; off >>= 1) p += __shfl_down(p, off);
    if (ln == 0) myeta_s = tanhf(p + h2b[0]);
  }
  __syncthreads();

  if (t == 0) {
    float m = logits_s[0];
    for (int a = 1; a < NACT; ++a) m = fmaxf(m, logits_s[a]);
    float e[NACT];
    float ssum = 0.f;
    for (int a = 0; a < NACT; ++a) { e[a] = expf(logits_s[a] - m); ssum += e[a]; }
    const float inv = 1.f / ssum;
    for (int a = 0; a < NACT; ++a) act_dis[(size_t)b * NACT + a] = e[a] * inv;
  }
  __syncthreads();
  const float me = myeta_s;
  g[(size_t)b * REC + t] = fmaf(me, mw[t], mb[t]) * hsh[t];
}

// ---------------------------------------------------------------------------
// Pass 2: hebb_out = clip(hebb + rv[b,i]*g[b,j]); reverse of pass-1 read
// order (i desc slow, batch desc fast) to consume the L3-LRU-hot tail; nt
// hints keep the streams from evicting what's about to be read.  (R3-proven)
__global__ __launch_bounds__(256) void k_hebb(
    const float* __restrict__ hebb, const float* __restrict__ rv,
    const float* __restrict__ g, float* __restrict__ out) {
  const int b  = 63 - (int)blockIdx.x;
  const int i0 = (127 - (int)blockIdx.y) * 8;
  const int j0 = threadIdx.x * 4;
  const f4 gv = *(const f4*)(g + (size_t)b * REC + j0);
  const float* __restrict__ rvb = rv + (size_t)b * REC;
  const size_t base = ((size_t)b * REC + i0) * REC + j0;
#pragma unroll
  for (int ii = 0; ii < 8; ++ii) {
    const float r = rvb[i0 + ii];
    const f4 hv = nt_load((const f4*)(hebb + base + (size_t)ii * REC));
    f4 o;
    o.x = fminf(fmaxf(fmaf(r, gv.x, hv.x), -CLIPVAL), CLIPVAL);
    o.y = fminf(fmaxf(fmaf(r, gv.y, hv.y), -CLIPVAL), CLIPVAL);
    o.z = fminf(fmaxf(fmaf(r, gv.z, hv.z), -CLIPVAL), CLIPVAL);
    o.w = fminf(fmaxf(fmaf(r, gv.w, hv.w), -CLIPVAL), CLIPVAL);
    nt_store((f4*)(out + base + (size_t)ii * REC), o);
  }
}

// ---------------------------------------------------------------------------
extern "C" void kernel_launch(void* const* d_in, const int* in_sizes, int n_in,
                              void* d_out, int out_size, void* d_ws, size_t ws_size,
                              hipStream_t stream) {
  const float* x     = (const float*)d_in[0];
  const float* rv    = (const float*)d_in[1];
  const float* hebb  = (const float*)d_in[2];
  const float* w     = (const float*)d_in[3];
  const float* alpha = (const float*)d_in[4];
  const float* W0    = (const float*)d_in[5];
  const float* b0    = (const float*)d_in[6];
  const float* W1    = (const float*)d_in[7];
  const float* b1    = (const float*)d_in[8];
  const float* h2w   = (const float*)d_in[9];
  const float* h2b   = (const float*)d_in[10];
  const float* mw    = (const float*)d_in[11];
  const float* mb    = (const float*)d_in[12];

  float* out_act  = (float*)d_out;               // 64*18
  float* out_hact = out_act + (size_t)BS * NACT; // 64*1024
  float* out_hebb = out_hact + (size_t)BS * REC; // 64*1024*1024

  float* part = (float*)d_ws;                    // 64*17*1024
  float* g    = part + (size_t)BS * NSLOT * REC; // 64*1024

  k_pass1<<<512, 256, 0, stream>>>(rv, hebb, w, alpha, x, W0, part);
  k_head<<<BS, 1024, 0, stream>>>(part, b0, W1, b1, h2w, h2b, mw, mb,
                                  out_hact, out_act, g);
  k_hebb<<<dim3(64, 128), 256, 0, stream>>>(hebb, rv, g, out_hebb);
}

// Round 10
// 155.129 us; speedup vs baseline: 1.3924x; 1.0278x over previous
//
#include <hip/hip_runtime.h>
#include <cmath>

constexpr int ISIZE = 512;
constexpr int REC   = 1024;
constexpr int NACT  = 18;
constexpr int BS    = 64;
constexpr float CLIPVAL = 2.0f;

constexpr int NSLOT = 17;  // 16 hebb i-chunk partials + 1 x@W0^T partial

typedef float f4 __attribute__((ext_vector_type(4)));

__device__ __forceinline__ f4 nt_load(const f4* p) {
#if __has_builtin(__builtin_nontemporal_load)
  return __builtin_nontemporal_load(p);
#else
  return *p;
#endif
}
__device__ __forceinline__ void nt_store(f4* p, f4 v) {
#if __has_builtin(__builtin_nontemporal_store)
  __builtin_nontemporal_store(v, p);
#else
  *p = v;
#endif
}

// ---------------------------------------------------------------------------
// Pass 1, single dispatch of 576 blocks (R3-proven, best measured: 155.5 us):
//   blocks 0..511 : hebb partials. Block = (ic, jh, bg): 64 i-rows x 512 j x
//                   4 batches. Each thread: 4 j (float4) x 2 batches in regs.
//                   bg is the FASTEST block dim so 16 concurrent blocks share
//                   the same w/alpha slice (L2/L3-hot); w/alpha cache traffic
//                   drops 4x vs one-batch-per-block.
//   blocks 512..575: x @ W0^T tiled GEMM (32b x 32j tiles, LDS-transposed W0),
//                   writes partial slot 16.
__global__ __launch_bounds__(256) void k_pass1(
    const float* __restrict__ rv, const float* __restrict__ hebb,
    const float* __restrict__ w, const float* __restrict__ alpha,
    const float* __restrict__ x, const float* __restrict__ W0,
    float* __restrict__ part) {
  const int id = blockIdx.x;
  const int t  = threadIdx.x;

  if (id < 512) {
    const int bg = id & 15;          // fastest: shares w/alpha across batches
    const int jh = (id >> 4) & 1;
    const int ic = id >> 5;
    const int b0 = bg * 4, i0 = ic * 64;
    const int jl = t & 127, bl = t >> 7;   // 128 j-lanes x 2 batch-lanes
    const int j0 = jh * 512 + jl * 4;
    const int ba = b0 + bl * 2;            // this thread's 2 batches: ba, ba+1

    __shared__ float rvs[4][64];
    rvs[t >> 6][t & 63] = rv[(size_t)(b0 + (t >> 6)) * REC + i0 + (t & 63)];
    __syncthreads();

    f4 a0 = {0.f, 0.f, 0.f, 0.f}, a1 = {0.f, 0.f, 0.f, 0.f};
    const float* __restrict__ wp  = w     + (size_t)i0 * REC + j0;
    const float* __restrict__ ap  = alpha + (size_t)i0 * REC + j0;
    const float* __restrict__ hp0 = hebb + ((size_t)ba * REC + i0) * REC + j0;
    const float* __restrict__ hp1 = hp0 + (size_t)REC * REC;
    const float* __restrict__ r0s = &rvs[bl * 2][0];
    const float* __restrict__ r1s = &rvs[bl * 2 + 1][0];

#pragma unroll 4
    for (int ii = 0; ii < 64; ++ii) {
      const f4 wv = *(const f4*)(wp  + (size_t)ii * REC);
      const f4 av = *(const f4*)(ap  + (size_t)ii * REC);
      const f4 h0 = *(const f4*)(hp0 + (size_t)ii * REC);
      const f4 h1 = *(const f4*)(hp1 + (size_t)ii * REC);
      const float r0 = r0s[ii], r1 = r1s[ii];
      a0.x = fmaf(r0, fmaf(av.x, h0.x, wv.x), a0.x);
      a0.y = fmaf(r0, fmaf(av.y, h0.y, wv.y), a0.y);
      a0.z = fmaf(r0, fmaf(av.z, h0.z, wv.z), a0.z);
      a0.w = fmaf(r0, fmaf(av.w, h0.w, wv.w), a0.w);
      a1.x = fmaf(r1, fmaf(av.x, h1.x, wv.x), a1.x);
      a1.y = fmaf(r1, fmaf(av.y, h1.y, wv.y), a1.y);
      a1.z = fmaf(r1, fmaf(av.z, h1.z, wv.z), a1.z);
      a1.w = fmaf(r1, fmaf(av.w, h1.w, wv.w), a1.w);
    }
    *(f4*)(part + ((size_t)ba * NSLOT + ic) * REC + j0)       = a0;
    *(f4*)(part + ((size_t)(ba + 1) * NSLOT + ic) * REC + j0) = a1;

  } else {
    // x @ W0^T -> part slot 16.  idx: 32 j-tiles x 2 batch-halves.
    const int idx = id - 512;
    const int jt = idx & 31, bg2 = idx >> 5;
    const int J0 = jt * 32, B0 = bg2 * 32;
    const int tx = t & 31, ty = t >> 5;    // tx: j/k lane, ty: 0..7
    __shared__ float w0s[32][33];          // [k][j], padded
    __shared__ float xs[32][33];           // [b][k], padded
    float acc[4] = {0.f, 0.f, 0.f, 0.f};
    for (int kk = 0; kk < ISIZE; kk += 32) {
#pragma unroll
      for (int r = 0; r < 32; r += 8) {
        w0s[tx][ty + r] = W0[(size_t)(J0 + ty + r) * ISIZE + kk + tx];
        xs[ty + r][tx]  = x [(size_t)(B0 + ty + r) * ISIZE + kk + tx];
      }
      __syncthreads();
#pragma unroll
      for (int k = 0; k < 32; ++k) {
        const float w0v = w0s[k][tx];
#pragma unroll
        for (int q = 0; q < 4; ++q)
          acc[q] = fmaf(xs[ty * 4 + q][k], w0v, acc[q]);
      }
      __syncthreads();
    }
#pragma unroll
    for (int q = 0; q < 4; ++q)
      part[((size_t)(B0 + ty * 4 + q) * NSLOT + 16) * REC + J0 + tx] = acc[q];
  }
}

// ---------------------------------------------------------------------------
// Per-batch head, 1024 threads: reduce 17 partials + b0 -> tanh -> hactiv;
// logits (wave-per-action), myeta, softmax (t0), g.
__global__ __launch_bounds__(1024) void k_head(
    const float* __restrict__ part, const float* __restrict__ b0,
    const float* __restrict__ W1, const float* __restrict__ b1,
    const float* __restrict__ h2w, const float* __restrict__ h2b,
    const float* __restrict__ mw, const float* __restrict__ mb,
    float* __restrict__ hact, float* __restrict__ act_dis,
    float* __restrict__ g) {
  const int b = blockIdx.x;
  const int t = threadIdx.x;         // == j
  __shared__ float hsh[REC];
  __shared__ float logits_s[32];
  __shared__ float myeta_s;

  float s = b0[t];
  const float* __restrict__ pb = part + (size_t)b * NSLOT * REC + t;
#pragma unroll
  for (int sl = 0; sl < NSLOT; ++sl) s += pb[(size_t)sl * REC];
  const float h = tanhf(s);
  hact[(size_t)b * REC + t] = h;
  hsh[t] = h;
  __syncthreads();

  const int wv = t >> 6, ln = t & 63;
  for (int a = wv; a < NACT; a += 16) {
    const float* __restrict__ w1a = W1 + (size_t)a * REC;
    float p = 0.f;
#pragma unroll
    for (int c = 0; c < 16; ++c) p = fmaf(hsh[c * 64 + ln], w1a[c * 64 + ln], p);
#pragma unroll
    for (int off = 32; off; off >>= 1) p += __shfl_down(p, off);
    if (ln == 0) logits_s[a] = p + b1[a];
  }
  if (wv == 0) {
    float p = 0.f;
#pragma unroll
    for (int c = 0; c < 16; ++c) p = fmaf(hsh[c * 64 + ln], h2w[c * 64 + ln], p);
#pragma unroll
    for (int off = 32; off; off >>= 1) p += __shfl_down(p, off);
    if (ln == 0) myeta_s = tanhf(p + h2b[0]);
  }
  __syncthreads();

  if (t == 0) {
    float m = logits_s[0];
    for (int a = 1; a < NACT; ++a) m = fmaxf(m, logits_s[a]);
    float e[NACT];
    float ssum = 0.f;
    for (int a = 0; a < NACT; ++a) { e[a] = expf(logits_s[a] - m); ssum += e[a]; }
    const float inv = 1.f / ssum;
    for (int a = 0; a < NACT; ++a) act_dis[(size_t)b * NACT + a] = e[a] * inv;
  }

  const float me = myeta_s;
  g[(size_t)b * REC + t] = fmaf(me, mw[t], mb[t]) * hsh[t];
}

// ---------------------------------------------------------------------------
// Pass 2: hebb_out = clip(hebb + rv[b,i]*g[b,j]).
// Block mapping REVERSES pass-1's global hebb read order (i-chunk slow-desc,
// batch fast-desc) so reads start at the L3-LRU-hot tail. Non-temporal
// loads+stores keep pass-2 from evicting the resident pass-1 lines.
__global__ __launch_bounds__(256) void k_hebb(
    const float* __restrict__ hebb, const float* __restrict__ rv,
    const float* __restrict__ g, float* __restrict__ out) {
  const int b  = 63 - (int)blockIdx.x;          // batch: fastest, descending
  const int i0 = (127 - (int)blockIdx.y) * 8;   // i-chunk: slow, descending
  const int j0 = threadIdx.x * 4;
  const f4 gv = *(const f4*)(g + (size_t)b * REC + j0);
  const float* __restrict__ rvb = rv + (size_t)b * REC;
  const size_t base = ((size_t)b * REC + i0) * REC + j0;
#pragma unroll
  for (int ii = 0; ii < 8; ++ii) {
    const float r = rvb[i0 + ii];
    const f4 hv = nt_load((const f4*)(hebb + base + (size_t)ii * REC));
    f4 o;
    o.x = fminf(fmaxf(fmaf(r, gv.x, hv.x), -CLIPVAL), CLIPVAL);
    o.y = fminf(fmaxf(fmaf(r, gv.y, hv.y), -CLIPVAL), CLIPVAL);
    o.z = fminf(fmaxf(fmaf(r, gv.z, hv.z), -CLIPVAL), CLIPVAL);
    o.w = fminf(fmaxf(fmaf(r, gv.w, hv.w), -CLIPVAL), CLIPVAL);
    nt_store((f4*)(out + base + (size_t)ii * REC), o);
  }
}

// ---------------------------------------------------------------------------
extern "C" void kernel_launch(void* const* d_in, const int* in_sizes, int n_in,
                              void* d_out, int out_size, void* d_ws, size_t ws_size,
                              hipStream_t stream) {
  const float* x     = (const float*)d_in[0];
  const float* rv    = (const float*)d_in[1];
  const float* hebb  = (const float*)d_in[2];
  const float* w     = (const float*)d_in[3];
  const float* alpha = (const float*)d_in[4];
  const float* W0    = (const float*)d_in[5];
  const float* b0    = (const float*)d_in[6];
  const float* W1    = (const float*)d_in[7];
  const float* b1    = (const float*)d_in[8];
  const float* h2w   = (const float*)d_in[9];
  const float* h2b   = (const float*)d_in[10];
  const float* mw    = (const float*)d_in[11];
  const float* mb    = (const float*)d_in[12];

  float* out_act  = (float*)d_out;               // 64*18
  float* out_hact = out_act + (size_t)BS * NACT; // 64*1024
  float* out_hebb = out_hact + (size_t)BS * REC; // 64*1024*1024

  float* part = (float*)d_ws;                    // 64*17*1024
  float* g    = part + (size_t)BS * NSLOT * REC; // 64*1024

  k_pass1<<<576, 256, 0, stream>>>(rv, hebb, w, alpha, x, W0, part);
  k_head<<<BS, 1024, 0, stream>>>(part, b0, W1, b1, h2w, h2b, mw, mb,
                                  out_hact, out_act, g);
  k_hebb<<<dim3(64, 128), 256, 0, stream>>>(hebb, rv, g, out_hebb);
}